// Round 2
// baseline (111.133 us; speedup 1.0000x reference)
//
#include <hip/hip_runtime.h>
#include <hip/hip_fp16.h>
#include <math.h>

// NSITES=100000, NYEARS=20, NVIS=2, HDIM=64
#define HDIM  64
#define NPAIR 2000000
#define NVEC  (NPAIR / 2)      // 1M float4 groups (2 pairs each)
#define PVEC  4                // groups per thread -> 8 pairs/thread
#define NT    (NVEC / PVEC)    // 250,000 threads
#define BLOCK 256
#define GRID  ((NT + BLOCK - 1) / BLOCK)   // 977 blocks -> 112 stray threads

// 33x33 bilinear table over (x,y) in [-1,1]^2, one half2(psi_logit, hd)
// per vertex (biases folded in). Error budget (logit): bilinear 4*h^2/8 =
// 2e-3 (h=1/16) + fp16 table quant (~2e-3 typ) -> output err ~2-4e-3 on
// top of 3.9e-3 bf16 floor; threshold 1.35e-2.
#define GP     33
#define GCELLS 32
#define TSIZE  (GP * GP)       // 1089 vertices * 4 B = 4.4 KB
#define SCALE  16.0f           // (x+1)*16 in [0,32]

// clang vector types: __builtin_nontemporal_load/store require real
// vector-of-float types, not HIP_vector_type structs.
typedef float vf4 __attribute__((ext_vector_type(4)));
typedef float vf2 __attribute__((ext_vector_type(2)));

#define LOG2E 1.44269504088896340736f
#if __has_builtin(__builtin_amdgcn_exp2f)
#define EXP2(x) __builtin_amdgcn_exp2f(x)
#else
#define EXP2(x) exp2f(x)
#endif

__device__ __forceinline__ float fast_sigmoid(float x) {
    return __builtin_amdgcn_rcpf(1.0f + EXP2(x * (-LOG2E)));
}

// ---- Kernel 1: build the packed table (exact expf ELU). 5 blocks. ----
__global__ __launch_bounds__(256) void build_table(
    const float* __restrict__ W_h,   // [64,2]
    const float* __restrict__ b_h,   // [64]
    const float* __restrict__ W_psi, // [64]
    const float* __restrict__ b_psi, // [1]
    const float* __restrict__ W_p,   // [65]
    const float* __restrict__ b_p,   // [1]
    __half2* __restrict__ T)         // [TSIZE] = (psi_logit, hd)
{
    const int idx = blockIdx.x * 256 + threadIdx.x;
    if (idx >= TSIZE) return;
    const int iy = idx / GP, ix = idx % GP;
    const float x = (float)ix * (1.0f / SCALE) - 1.0f;
    const float y = (float)iy * (1.0f / SCALE) - 1.0f;
    float psi_l = b_psi[0];
    float hd    = b_p[0];
#pragma unroll 8
    for (int h = 0; h < HDIM; ++h) {
        const float z = fmaf(W_h[2 * h], x, fmaf(W_h[2 * h + 1], y, b_h[h]));
        const float e = (z > 0.0f) ? z : (expf(z) - 1.0f);
        psi_l = fmaf(W_psi[h], e, psi_l);
        hd    = fmaf(W_p[h], e, hd);
    }
    T[idx] = __floats2half2_rn(psi_l, hd);
}

// ---- Kernel 2: stream pairs, bilinear-gather packed half2 from LDS. ----
__device__ __forceinline__ float2 lookup(const __half2* __restrict__ sT,
                                         float x, float y) {
    const float gx = fmaf(x, SCALE, SCALE);
    const float gy = fmaf(y, SCALE, SCALE);
    int ix = (int)gx;                       // gx >= 0 by construction
    int iy = (int)gy;
    ix = max(0, min(ix, GCELLS - 1));
    iy = max(0, min(iy, GCELLS - 1));
    const __half2 fx2 = __float2half2_rn(gx - (float)ix);
    const __half2 fy2 = __float2half2_rn(gy - (float)iy);
    const int b = iy * GP + ix;
    const __half2 c00 = sT[b],      c01 = sT[b + 1];       // ds_read_b32 x4
    const __half2 c10 = sT[b + GP], c11 = sT[b + GP + 1];
    const __half2 t0 = __hfma2(fx2, __hsub2(c01, c00), c00); // v_pk_fma_f16
    const __half2 t1 = __hfma2(fx2, __hsub2(c11, c10), c10);
    const __half2 r  = __hfma2(fy2, __hsub2(t1, t0), t0);
    return __half22float2(r);               // (psi_logit, hd)
}

// launch_bounds(256,4): 128-VGPR budget. The (256,8)/64-VGPR version
// couldn't hold 8 in-flight float4 loads + interleaved lookups without
// serializing; 16 waves/CU is plenty for a streaming kernel.
__global__ __launch_bounds__(BLOCK, 4) void fused_net(
    const vf4* __restrict__ sxy,      // (x0,y0,x1,y1) per group
    const vf4* __restrict__ oxy,      // (o00,o01,o10,o11) per group
    const __half2* __restrict__ T,    // global packed table
    const float*  __restrict__ W_p,   // [65] -> wx = W_p[64]
    vf2* __restrict__ out_psi,        // NVEC float2
    vf4* __restrict__ out_p)          // NVEC float4
{
    __shared__ __align__(16) __half2 sT[TSIZE];   // 4.4 KB

    const int tid = blockIdx.x * BLOCK + threadIdx.x;
    // Clamp the load index: stray threads (tid >= NT) re-load thread
    // NT-1's data in-bounds, overlap the barrier, then exit before stores.
    const int g = min(tid, NT - 1);

    // Issue ALL streaming loads first (nontemporal: read-once data, keep
    // the table + L1/L2 unpolluted). HBM latency overlaps table staging.
    vf4 s[PVEC], o[PVEC];
#pragma unroll
    for (int i = 0; i < PVEC; ++i) {
        s[i] = __builtin_nontemporal_load(&sxy[g + i * NT]);
        o[i] = __builtin_nontemporal_load(&oxy[g + i * NT]);
    }
    const float wx = W_p[HDIM];      // wave-uniform s_load

    for (int k = threadIdx.x; k < TSIZE; k += BLOCK) sT[k] = T[k];
    __syncthreads();

    if (tid >= NT) return;           // OOB-write guard

#pragma unroll
    for (int i = 0; i < PVEC; ++i) {
        const float2 rA = lookup(sT, s[i][0], s[i][1]);
        const float2 rB = lookup(sT, s[i][2], s[i][3]);

        vf2 ps;
        ps[0] = fast_sigmoid(rA.x);
        ps[1] = fast_sigmoid(rB.x);
        __builtin_nontemporal_store(ps, &out_psi[tid + i * NT]);

        vf4 pp;
        pp[0] = fast_sigmoid(fmaf(o[i][0], wx, rA.y));
        pp[1] = fast_sigmoid(fmaf(o[i][1], wx, rA.y));
        pp[2] = fast_sigmoid(fmaf(o[i][2], wx, rB.y));
        pp[3] = fast_sigmoid(fmaf(o[i][3], wx, rB.y));
        __builtin_nontemporal_store(pp, &out_p[tid + i * NT]);
    }
}

extern "C" void kernel_launch(void* const* d_in, const int* in_sizes, int n_in,
                              void* d_out, int out_size, void* d_ws, size_t ws_size,
                              hipStream_t stream) {
    const float* sxy   = (const float*)d_in[0];
    const float* oxy   = (const float*)d_in[1];
    // d_in[2] = p : unused by the reference computation
    const float* W_h   = (const float*)d_in[3];
    const float* b_h   = (const float*)d_in[4];
    const float* W_psi = (const float*)d_in[5];
    const float* b_psi = (const float*)d_in[6];
    const float* W_p   = (const float*)d_in[7];
    const float* b_p   = (const float*)d_in[8];

    __half2* T = (__half2*)d_ws;           // 4.4 KB of the workspace

    build_table<<<(TSIZE + 255) / 256, 256, 0, stream>>>(
        W_h, b_h, W_psi, b_psi, W_p, b_p, T);

    float* out = (float*)d_out;            // [psi(2M) | p_out(4M)]
    fused_net<<<GRID, BLOCK, 0, stream>>>(
        (const vf4*)sxy, (const vf4*)oxy, T, W_p,
        (vf2*)out, (vf4*)(out + NPAIR));
}